// Round 2
// baseline (18873.807 us; speedup 1.0000x reference)
//
#include <hip/hip_runtime.h>
#include <hip/hip_bf16.h>

#define B_ 256
#define T_ 512
#define D_ 256
#define H_ 1024
#define C_ 10

typedef __attribute__((ext_vector_type(8))) short short8;
typedef __attribute__((ext_vector_type(4))) float floatx4;

static __device__ __forceinline__ unsigned short f2bf(float f) {
    __hip_bfloat16 b = __float2bfloat16(f);
    return *reinterpret_cast<unsigned short*>(&b);
}
static __device__ __forceinline__ float bf2f(unsigned short u) {
    unsigned int v = ((unsigned int)u) << 16;
    return __uint_as_float(v);
}
static __device__ __forceinline__ float fast_tanh(float x) {
    // tanh(x) = 1 - 2/(e^{2x}+1); saturates correctly at +-inf via rcp(inf)=0
    float e = __expf(2.f * x);
    return 1.f - __fdividef(2.f, e + 1.f);
}

// ---------------------------------------------------------------------------
// proj3[v][col] = sum_d emb[v][d] * Wx[d][col] + b[col], col in [0,4096)
// ---------------------------------------------------------------------------
__global__ void lstm_proj3(const float* __restrict__ emb,
                           const float* __restrict__ Wgx, const float* __restrict__ Wix,
                           const float* __restrict__ Wfx, const float* __restrict__ Wox,
                           const float* __restrict__ bg, const float* __restrict__ bi,
                           const float* __restrict__ bf_, const float* __restrict__ bo,
                           float* __restrict__ proj3) {
    int col = blockIdx.x * 256 + threadIdx.x;  // 0..4095
    int v = blockIdx.y;                        // 0..2
    int gate = col >> 10;
    int j = col & (H_ - 1);
    const float* Wx = (gate == 0) ? Wgx : (gate == 1) ? Wix : (gate == 2) ? Wfx : Wox;
    const float* bb = (gate == 0) ? bg : (gate == 1) ? bi : (gate == 2) ? bf_ : bo;
    float acc = bb[j];
    for (int d = 0; d < D_; ++d)
        acc += emb[v * D_ + d] * Wx[(size_t)d * H_ + j];
    proj3[(size_t)v * 4096 + col] = acc;
}

// ---------------------------------------------------------------------------
// Persistent LSTM recurrence. Cooperative launch, 256 WGs x 256 threads,
// 1 WG/CU. WG (r, c): rows r*128..r*128+127, h-cols c*8..c*8+7 (x4 gates).
// B-slice (32 gate-cols x 1024 k, bf16, XOR-swizzled) lives in LDS for the
// whole run. c lives in registers. h ping-pongs in global bf16; per-row-block
// (128 WG) barrier via per-step atomic counters.
// ---------------------------------------------------------------------------
__launch_bounds__(256, 1)
__global__ void lstm_persist(const float* __restrict__ Wg, const float* __restrict__ Wi,
                             const float* __restrict__ Wf, const float* __restrict__ Wo,
                             const float* __restrict__ proj3, const int* __restrict__ x,
                             unsigned short* __restrict__ hb0, unsigned short* __restrict__ hb1,
                             int* __restrict__ ct) {
    __shared__ unsigned short Blds[32 * 1024];  // 64 KB  [q][k^((q&7)<<3)]
    __shared__ float zbuf[128][33];             // 16.9 KB
    __shared__ float projL[3][32];              // 384 B

    const int bid = blockIdx.x;
    const int r = bid >> 7;    // 0..1
    const int cc = bid & 127;  // 0..127
    const int r0 = r * 128;
    const int j0 = cc * 8;
    const int tid = threadIdx.x;

    // ---- one-time: pack B slice into LDS (bf16, swizzled) ----
    {
        const int q = tid & 31;       // gate-col 0..31
        const int g = q >> 3;
        const int j = j0 + (q & 7);
        const float* W = (g == 0) ? Wg : (g == 1) ? Wi : (g == 2) ? Wf : Wo;
        const int kbase = tid >> 5;   // 0..7
        const int xq = (q & 7) << 3;  // ushort-index xor
        for (int it = 0; it < 128; ++it) {
            int k = kbase + 8 * it;
            Blds[q * 1024 + (k ^ xq)] = f2bf(W[(size_t)k * H_ + j]);
        }
    }
    if (tid < 96) {
        int v = tid >> 5, q = tid & 31;
        projL[v][q] = proj3[(size_t)v * 4096 + (size_t)(q >> 3) * H_ + j0 + (q & 7)];
    }
    __syncthreads();

    // wave/lane geometry for GEMM
    const int w = tid >> 6;
    const int lane = tid & 63;
    const int lr = lane & 15;
    const int lkb = (lane >> 4) * 8;
    const int xorq = (lr & 7) << 3;
    const unsigned short* Bq0 = Blds + lr * 1024;
    const unsigned short* Bq1 = Blds + (16 + lr) * 1024;
    const size_t arow0 = (size_t)(r0 + 32 * w + lr) * H_ + lkb;
    const size_t arow1 = arow0 + (size_t)16 * H_;

    // combine geometry
    const int jc = tid & 7;
    const int rt = tid >> 3;  // 0..31
    float creg[4] = {0.f, 0.f, 0.f, 0.f};

    unsigned short* hbuf[2] = {hb0, hb1};
    int* ctr = ct + (size_t)r * T_;

    for (int t = 0; t < T_; ++t) {
        const unsigned short* h_in = hbuf[t & 1];
        unsigned short* h_out = hbuf[(t + 1) & 1];

        // tokens (read-only input, no dependency on h)
        int tok[4];
        #pragma unroll
        for (int i = 0; i < 4; ++i)
            tok[i] = x[(size_t)(r0 + rt + 32 * i) * T_ + t];

        // wait for previous step's h from the whole row-block
        if (t > 0) {
            if (tid == 0) {
                while (__hip_atomic_load(&ctr[t - 1], __ATOMIC_ACQUIRE,
                                         __HIP_MEMORY_SCOPE_AGENT) < 128) {}
                __threadfence();  // acquire: invalidate stale L1/L2 lines
            }
            __syncthreads();
        }

        // GEMM: z_pre = h_in @ B  (per wave: M=32 rows, N=32 gate-cols)
        floatx4 acc[2][2] = {};
        #pragma unroll 4
        for (int kk = 0; kk < H_; kk += 32) {
            short8 a0 = *(const short8*)(h_in + arow0 + kk);
            short8 a1 = *(const short8*)(h_in + arow1 + kk);
            int ki = (kk + lkb) ^ xorq;
            short8 b0 = *(const short8*)(Bq0 + ki);
            short8 b1 = *(const short8*)(Bq1 + ki);
            acc[0][0] = __builtin_amdgcn_mfma_f32_16x16x32_bf16(a0, b0, acc[0][0], 0, 0, 0);
            acc[0][1] = __builtin_amdgcn_mfma_f32_16x16x32_bf16(a0, b1, acc[0][1], 0, 0, 0);
            acc[1][0] = __builtin_amdgcn_mfma_f32_16x16x32_bf16(a1, b0, acc[1][0], 0, 0, 0);
            acc[1][1] = __builtin_amdgcn_mfma_f32_16x16x32_bf16(a1, b1, acc[1][1], 0, 0, 0);
        }

        // acc -> zbuf
        #pragma unroll
        for (int m = 0; m < 2; ++m)
            #pragma unroll
            for (int n = 0; n < 2; ++n)
                #pragma unroll
                for (int i = 0; i < 4; ++i)
                    zbuf[32 * w + 16 * m + 4 * (lane >> 4) + i][16 * n + lr] = acc[m][n][i];
        __syncthreads();

        // gate combine; c stays in registers
        #pragma unroll
        for (int i = 0; i < 4; ++i) {
            int rl = rt + 32 * i;
            const float* pl = projL[tok[i]];
            float zg = fast_tanh(zbuf[rl][jc] + pl[jc]);
            float zi = fast_tanh(zbuf[rl][8 + jc] + pl[8 + jc]);
            float zf = fast_tanh(zbuf[rl][16 + jc] + pl[16 + jc]);
            float zo = fast_tanh(zbuf[rl][24 + jc] + pl[24 + jc]);
            float cv = zg * zi + creg[i] * zf;
            creg[i] = cv;
            h_out[(size_t)(r0 + rl) * H_ + j0 + jc] = f2bf(fast_tanh(cv) * zo);
        }
        __syncthreads();  // protect zbuf; also drains vmem before arrive

        if (tid == 0) {
            __threadfence();  // release: make h_out visible device-wide
            __hip_atomic_fetch_add(&ctr[t], 1, __ATOMIC_RELEASE, __HIP_MEMORY_SCOPE_AGENT);
        }
    }
}

// ---------------------------------------------------------------------------
// Final projection + log_softmax. One block (64 threads) per batch row.
// ---------------------------------------------------------------------------
__global__ void lstm_final(const unsigned short* __restrict__ h,  // bf16 256x1024
                           const float* __restrict__ Wp,          // 1024x10
                           const float* __restrict__ bp,          // 10
                           float* __restrict__ out) {             // 256x10
    int row = blockIdx.x;
    int lane = threadIdx.x;  // 0..63
    float acc[C_];
    #pragma unroll
    for (int cc = 0; cc < C_; ++cc) acc[cc] = 0.f;
    for (int k = lane; k < H_; k += 64) {
        float hv = bf2f(h[(size_t)row * H_ + k]);
        #pragma unroll
        for (int cc = 0; cc < C_; ++cc) acc[cc] += hv * Wp[(size_t)k * C_ + cc];
    }
    #pragma unroll
    for (int cc = 0; cc < C_; ++cc)
        #pragma unroll
        for (int off = 32; off > 0; off >>= 1)
            acc[cc] += __shfl_down(acc[cc], off);
    if (lane == 0) {
        float p[C_];
        float m = -1e30f;
        #pragma unroll
        for (int cc = 0; cc < C_; ++cc) {
            p[cc] = acc[cc] + bp[cc];
            m = fmaxf(m, p[cc]);
        }
        float se = 0.f;
        #pragma unroll
        for (int cc = 0; cc < C_; ++cc) se += expf(p[cc] - m);
        float lse = m + logf(se);
        #pragma unroll
        for (int cc = 0; cc < C_; ++cc) out[(size_t)row * C_ + cc] = p[cc] - lse;
    }
}

extern "C" void kernel_launch(void* const* d_in, const int* in_sizes, int n_in,
                              void* d_out, int out_size, void* d_ws, size_t ws_size,
                              hipStream_t stream) {
    const int* x = (const int*)d_in[0];
    const float* emb = (const float*)d_in[1];
    const float* W_gx = (const float*)d_in[2];
    const float* W_gh = (const float*)d_in[3];
    const float* b_g = (const float*)d_in[4];
    const float* W_ix = (const float*)d_in[5];
    const float* W_ih = (const float*)d_in[6];
    const float* b_i = (const float*)d_in[7];
    const float* W_fx = (const float*)d_in[8];
    const float* W_fh = (const float*)d_in[9];
    const float* b_f = (const float*)d_in[10];
    const float* W_ox = (const float*)d_in[11];
    const float* W_oh = (const float*)d_in[12];
    const float* b_o = (const float*)d_in[13];
    const float* W_ph = (const float*)d_in[14];
    const float* b_p = (const float*)d_in[15];
    float* out = (float*)d_out;

    // workspace layout
    char* ws = (char*)d_ws;
    float* proj3 = (float*)ws;
    size_t off = 3 * 4096 * sizeof(float);                                  // 48 KB
    unsigned short* hbuf0 = (unsigned short*)(ws + off); off += (size_t)B_ * H_ * 2;
    unsigned short* hbuf1 = (unsigned short*)(ws + off); off += (size_t)B_ * H_ * 2;
    int* ct = (int*)(ws + off); off += 2 * T_ * sizeof(int);                // 4 KB

    // 1. proj3 = emb @ Wx + b   (3 x 4096)
    lstm_proj3<<<dim3(16, 3), 256, 0, stream>>>(emb, W_gx, W_ix, W_fx, W_ox,
                                                b_g, b_i, b_f, b_o, proj3);
    // 2. zero h0 and barrier counters (every launch -> replay-safe)
    hipMemsetAsync(hbuf0, 0, (size_t)B_ * H_ * 2, stream);
    hipMemsetAsync(ct, 0, 2 * T_ * sizeof(int), stream);

    // 3. persistent recurrence (cooperative: all 256 WGs co-resident)
    {
        const float* a0 = W_gh; const float* a1 = W_ih;
        const float* a2 = W_fh; const float* a3 = W_oh;
        const float* a4 = proj3; const int* a5 = x;
        unsigned short* a6 = hbuf0; unsigned short* a7 = hbuf1;
        int* a8 = ct;
        void* args[] = {&a0, &a1, &a2, &a3, &a4, &a5, &a6, &a7, &a8};
        hipLaunchCooperativeKernel((const void*)lstm_persist, dim3(256), dim3(256),
                                   args, 0, stream);
    }

    // 4. final projection + log_softmax (h_512 lands in hbuf0: T_ even)
    lstm_final<<<B_, 64, 0, stream>>>(hbuf0, W_ph, b_p, out);
}

// Round 3
// 11989.627 us; speedup vs baseline: 1.5742x; 1.5742x over previous
//
#include <hip/hip_runtime.h>
#include <hip/hip_bf16.h>

#define B_ 256
#define T_ 512
#define D_ 256
#define H_ 1024
#define C_ 10

typedef __attribute__((ext_vector_type(8))) short short8;
typedef __attribute__((ext_vector_type(4))) float floatx4;

static __device__ __forceinline__ unsigned short f2bf(float f) {
    __hip_bfloat16 b = __float2bfloat16(f);
    return *reinterpret_cast<unsigned short*>(&b);
}
static __device__ __forceinline__ float bf2f(unsigned short u) {
    unsigned int v = ((unsigned int)u) << 16;
    return __uint_as_float(v);
}
static __device__ __forceinline__ float fast_tanh(float x) {
    float e = __expf(2.f * x);
    return 1.f - __fdividef(2.f, e + 1.f);
}

// ---------------------------------------------------------------------------
// proj3[v][col] = sum_d emb[v][d] * Wx[d][col] + b[col], col in [0,4096)
// ---------------------------------------------------------------------------
__global__ void lstm_proj3(const float* __restrict__ emb,
                           const float* __restrict__ Wgx, const float* __restrict__ Wix,
                           const float* __restrict__ Wfx, const float* __restrict__ Wox,
                           const float* __restrict__ bg, const float* __restrict__ bi,
                           const float* __restrict__ bf_, const float* __restrict__ bo,
                           float* __restrict__ proj3) {
    int col = blockIdx.x * 256 + threadIdx.x;  // 0..4095
    int v = blockIdx.y;                        // 0..2
    int gate = col >> 10;
    int j = col & (H_ - 1);
    const float* Wx = (gate == 0) ? Wgx : (gate == 1) ? Wix : (gate == 2) ? Wfx : Wox;
    const float* bb = (gate == 0) ? bg : (gate == 1) ? bi : (gate == 2) ? bf_ : bo;
    float acc = bb[j];
    for (int d = 0; d < D_; ++d)
        acc += emb[v * D_ + d] * Wx[(size_t)d * H_ + j];
    proj3[(size_t)v * 4096 + col] = acc;
}

// ---------------------------------------------------------------------------
// Persistent LSTM recurrence. Cooperative, 256 WGs x 256 threads, 1 WG/CU.
// WG (rb, cc): rows rb*64..+63, h-cols cc*16..+15 (x4 gates = 64 gate-cols).
// B-slice (64 gate-cols x 1024 k, bf16, XOR-swizzled) in LDS for the whole
// run (128 KB). c in registers. h ping-pongs in global bf16.
// Sync per row-block (64 WGs) per step: RELAXED spin + ONE acquire fence;
// syncthreads-drain + ONE release fence + RELAXED add. (Round-2 lesson: an
// ACQUIRE atomic inside the poll loop emits buffer_inv per iteration ->
// continuous L2 nuking was the 37us/step wall.)
// ---------------------------------------------------------------------------
__launch_bounds__(256, 1)
__global__ void lstm_persist(const float* __restrict__ Wg, const float* __restrict__ Wi,
                             const float* __restrict__ Wf, const float* __restrict__ Wo,
                             const float* __restrict__ proj3, const int* __restrict__ x,
                             unsigned short* __restrict__ hb0, unsigned short* __restrict__ hb1,
                             int* __restrict__ ct) {
    __shared__ unsigned short Blds[64 * 1024];  // 128 KB  [q][k ^ ((q&7)<<3)]
    __shared__ float zbuf[64][65];              // 16.6 KB
    __shared__ float projL[3][64];              // 768 B

    const int bid = blockIdx.x;
    const int rb = bid >> 6;   // 0..3 row-block
    const int cc = bid & 63;   // 0..63 col chunk
    const int r0 = rb * 64;
    const int j0 = cc * 16;
    const int tid = threadIdx.x;

    // ---- one-time: pack B slice into LDS (bf16, swizzled) ----
    {
        const int q = tid & 63;       // gate-col 0..63 (gate = q>>4, hcol = q&15)
        const int g = q >> 4;
        const int j = j0 + (q & 15);
        const float* W = (g == 0) ? Wg : (g == 1) ? Wi : (g == 2) ? Wf : Wo;
        const int kbase = tid >> 6;   // 0..3
        const int xq = (q & 7) << 3;
        for (int it = 0; it < 256; ++it) {
            int k = kbase + 4 * it;
            Blds[q * 1024 + (k ^ xq)] = f2bf(W[(size_t)k * H_ + j]);
        }
    }
    if (tid < 192) {
        int v = tid >> 6, q = tid & 63;
        projL[v][q] = proj3[(size_t)v * 4096 + (size_t)(q >> 4) * H_ + j0 + (q & 15)];
    }
    __syncthreads();

    // wave/lane geometry: 2x2 waves, each 32 rows x 32 gate-cols
    const int w = tid >> 6;
    const int wr = w >> 1, wc = w & 1;
    const int lane = tid & 63;
    const int lr = lane & 15;
    const int kq = lane >> 4;
    const int lkb = kq * 8;
    const int xorq = (lr & 7) << 3;
    const unsigned short* Bq0 = Blds + (size_t)(32 * wc + lr) * 1024;
    const unsigned short* Bq1 = Blds + (size_t)(32 * wc + 16 + lr) * 1024;
    const size_t arow0 = (size_t)(r0 + 32 * wr + lr) * H_ + lkb;
    const size_t arow1 = arow0 + (size_t)16 * H_;

    // combine geometry: thread -> rows {rr, rr+32}, h-cols {2hc, 2hc+1}
    const int hc = tid & 7;
    const int rr = tid >> 3;  // 0..31
    float creg[2][2] = {{0.f, 0.f}, {0.f, 0.f}};

    unsigned short* hbuf[2] = {hb0, hb1};
    int* ctr = ct + (size_t)rb * T_;

    for (int t = 0; t < T_; ++t) {
        const unsigned short* h_in = hbuf[t & 1];
        unsigned short* h_out = hbuf[(t + 1) & 1];

        // tokens: independent of h, load before the barrier
        int tok0 = x[(size_t)(r0 + rr) * T_ + t];
        int tok1 = x[(size_t)(r0 + rr + 32) * T_ + t];

        if (t > 0) {
            if (tid == 0) {
                while (__hip_atomic_load(&ctr[t - 1], __ATOMIC_RELAXED,
                                         __HIP_MEMORY_SCOPE_AGENT) < 64) {}
                __builtin_amdgcn_fence(__ATOMIC_ACQUIRE, "agent");  // ONE inv per step
            }
            __syncthreads();
        }

        // GEMM: z_pre = h_in @ B  (per wave: 32 rows x 32 gate-cols, K=1024)
        floatx4 acc[2][2] = {};
        #pragma unroll 4
        for (int kk = 0; kk < H_; kk += 32) {
            short8 a0 = *(const short8*)(h_in + arow0 + kk);
            short8 a1 = *(const short8*)(h_in + arow1 + kk);
            int ki = (kk + lkb) ^ xorq;
            short8 b0 = *(const short8*)(Bq0 + ki);
            short8 b1 = *(const short8*)(Bq1 + ki);
            acc[0][0] = __builtin_amdgcn_mfma_f32_16x16x32_bf16(a0, b0, acc[0][0], 0, 0, 0);
            acc[0][1] = __builtin_amdgcn_mfma_f32_16x16x32_bf16(a0, b1, acc[0][1], 0, 0, 0);
            acc[1][0] = __builtin_amdgcn_mfma_f32_16x16x32_bf16(a1, b0, acc[1][0], 0, 0, 0);
            acc[1][1] = __builtin_amdgcn_mfma_f32_16x16x32_bf16(a1, b1, acc[1][1], 0, 0, 0);
        }

        // acc -> zbuf
        #pragma unroll
        for (int m = 0; m < 2; ++m)
            #pragma unroll
            for (int n = 0; n < 2; ++n)
                #pragma unroll
                for (int i = 0; i < 4; ++i)
                    zbuf[32 * wr + 16 * m + 4 * kq + i][32 * wc + 16 * n + lr] = acc[m][n][i];
        __syncthreads();

        // gate combine; c stays in registers
        #pragma unroll
        for (int i = 0; i < 2; ++i) {
            int rl = rr + 32 * i;
            const float* pl = projL[i ? tok1 : tok0];
            unsigned int hpack = 0;
            #pragma unroll
            for (int b = 0; b < 2; ++b) {
                int jc = 2 * hc + b;
                float zg = fast_tanh(zbuf[rl][jc] + pl[jc]);
                float zi = fast_tanh(zbuf[rl][16 + jc] + pl[16 + jc]);
                float zf = fast_tanh(zbuf[rl][32 + jc] + pl[32 + jc]);
                float zo = fast_tanh(zbuf[rl][48 + jc] + pl[48 + jc]);
                float cv = zg * zi + creg[i][b] * zf;
                creg[i][b] = cv;
                hpack |= ((unsigned int)f2bf(fast_tanh(cv) * zo)) << (16 * b);
            }
            *(unsigned int*)(h_out + (size_t)(r0 + rl) * H_ + j0 + 2 * hc) = hpack;
        }
        __syncthreads();  // drains all waves' stores (waitcnt before barrier) + protects zbuf

        if (tid == 0) {
            __builtin_amdgcn_fence(__ATOMIC_RELEASE, "agent");  // ONE wbl2 per step
            __hip_atomic_fetch_add(&ctr[t], 1, __ATOMIC_RELAXED, __HIP_MEMORY_SCOPE_AGENT);
        }
    }
}

// ---------------------------------------------------------------------------
// Final projection + log_softmax. One block (64 threads) per batch row.
// ---------------------------------------------------------------------------
__global__ void lstm_final(const unsigned short* __restrict__ h,  // bf16 256x1024
                           const float* __restrict__ Wp,          // 1024x10
                           const float* __restrict__ bp,          // 10
                           float* __restrict__ out) {             // 256x10
    int row = blockIdx.x;
    int lane = threadIdx.x;  // 0..63
    float acc[C_];
    #pragma unroll
    for (int cc = 0; cc < C_; ++cc) acc[cc] = 0.f;
    for (int k = lane; k < H_; k += 64) {
        float hv = bf2f(h[(size_t)row * H_ + k]);
        #pragma unroll
        for (int cc = 0; cc < C_; ++cc) acc[cc] += hv * Wp[(size_t)k * C_ + cc];
    }
    #pragma unroll
    for (int cc = 0; cc < C_; ++cc)
        #pragma unroll
        for (int off = 32; off > 0; off >>= 1)
            acc[cc] += __shfl_down(acc[cc], off);
    if (lane == 0) {
        float p[C_];
        float m = -1e30f;
        #pragma unroll
        for (int cc = 0; cc < C_; ++cc) {
            p[cc] = acc[cc] + bp[cc];
            m = fmaxf(m, p[cc]);
        }
        float se = 0.f;
        #pragma unroll
        for (int cc = 0; cc < C_; ++cc) se += expf(p[cc] - m);
        float lse = m + logf(se);
        #pragma unroll
        for (int cc = 0; cc < C_; ++cc) out[(size_t)row * C_ + cc] = p[cc] - lse;
    }
}

extern "C" void kernel_launch(void* const* d_in, const int* in_sizes, int n_in,
                              void* d_out, int out_size, void* d_ws, size_t ws_size,
                              hipStream_t stream) {
    const int* x = (const int*)d_in[0];
    const float* emb = (const float*)d_in[1];
    const float* W_gx = (const float*)d_in[2];
    const float* W_gh = (const float*)d_in[3];
    const float* b_g = (const float*)d_in[4];
    const float* W_ix = (const float*)d_in[5];
    const float* W_ih = (const float*)d_in[6];
    const float* b_i = (const float*)d_in[7];
    const float* W_fx = (const float*)d_in[8];
    const float* W_fh = (const float*)d_in[9];
    const float* b_f = (const float*)d_in[10];
    const float* W_ox = (const float*)d_in[11];
    const float* W_oh = (const float*)d_in[12];
    const float* b_o = (const float*)d_in[13];
    const float* W_ph = (const float*)d_in[14];
    const float* b_p = (const float*)d_in[15];
    float* out = (float*)d_out;

    // workspace layout
    char* ws = (char*)d_ws;
    float* proj3 = (float*)ws;
    size_t off = 3 * 4096 * sizeof(float);
    unsigned short* hbuf0 = (unsigned short*)(ws + off); off += (size_t)B_ * H_ * 2;
    unsigned short* hbuf1 = (unsigned short*)(ws + off); off += (size_t)B_ * H_ * 2;
    int* ct = (int*)(ws + off); off += 4 * T_ * sizeof(int);

    // 1. proj3 = emb @ Wx + b   (3 x 4096)
    lstm_proj3<<<dim3(16, 3), 256, 0, stream>>>(emb, W_gx, W_ix, W_fx, W_ox,
                                                b_g, b_i, b_f, b_o, proj3);
    // 2. zero h0 and barrier counters (every launch -> replay-safe)
    hipMemsetAsync(hbuf0, 0, (size_t)B_ * H_ * 2, stream);
    hipMemsetAsync(ct, 0, 4 * T_ * sizeof(int), stream);

    // 3. persistent recurrence (cooperative: all 256 WGs co-resident)
    {
        const float* a0 = W_gh; const float* a1 = W_ih;
        const float* a2 = W_fh; const float* a3 = W_oh;
        const float* a4 = proj3; const int* a5 = x;
        unsigned short* a6 = hbuf0; unsigned short* a7 = hbuf1;
        int* a8 = ct;
        void* args[] = {&a0, &a1, &a2, &a3, &a4, &a5, &a6, &a7, &a8};
        hipLaunchCooperativeKernel((const void*)lstm_persist, dim3(256), dim3(256),
                                   args, 0, stream);
    }

    // 4. final projection + log_softmax (h_512 lands in hbuf0: T_ even)
    lstm_final<<<B_, 64, 0, stream>>>(hbuf0, W_ph, b_p, out);
}